// Round 1
// baseline (149.118 us; speedup 1.0000x reference)
//
#include <hip/hip_runtime.h>
#include <math.h>

#define H_  128
#define N_  64
#define L_  4096
#define B_  8
#define LC  128     // chunk length
#define NCH 32      // number of chunks (L_/LC)
#define TPB 256
#define MPL 8       // modes per lane

// One block per (b,h). Chunked parallel scan over L with N=64 complex modes.
// y[l] = Re(sum_n c_n * x_n[l]) + D*u[l],  x_n[l] = r_n x_n[l-1] + u[l]
// r = exp(step*Lambda);  c = (W/Lambda)*conj(s)/(|s|^2+EPS);  s = (1-r^L)/(1-r)
__global__ __launch_bounds__(TPB, 4)
void dss_fwd(const float* __restrict__ u,
             const float* __restrict__ Lre,
             const float* __restrict__ Lim,
             const float* __restrict__ Wri,
             const float* __restrict__ Dv,
             const float* __restrict__ lstep,
             float* __restrict__ out)
{
    __shared__ float su[L_];                 // staged u row (16 KB)
    __shared__ float sE[L_];                 // chunk end-states / carries, then y (16 KB)
    __shared__ float s_rre[N_], s_rim[N_];   // r
    __shared__ float s_cre[N_], s_cim[N_];   // c
    __shared__ float s_qre[N_], s_qim[N_];   // r^LC

    const int t  = threadIdx.x;
    const int bh = blockIdx.x;               // b*H + h
    const int h  = bh % H_;

    // stage u (coalesced float4)
    {
        const float4* up = reinterpret_cast<const float4*>(u + (size_t)bh * L_);
        float4* sp = reinterpret_cast<float4*>(su);
        #pragma unroll
        for (int i = 0; i < L_/4/TPB; ++i)
            sp[t + i*TPB] = up[t + i*TPB];
    }

    // per-(h,n) constants in double (one-time, wave 0)
    if (t < N_) {
        const int n = t;
        const float stepf = expf(lstep[h]);          // matches jnp.exp in f32
        const float a  = stepf * Lre[h*N_ + n];      // f32 to match P construction
        const float bp = stepf * Lim[h*N_ + n];
        const double ad = (double)a, bd = (double)bp;
        const double em = exp(ad);
        const double rre = em * cos(bd), rim = em * sin(bd);
        const double eL = exp(ad * (double)L_);
        const double rLre = eL * cos(bd * (double)L_), rLim = eL * sin(bd * (double)L_);
        // s = (1 - r^L) / (1 - r)
        const double nre = 1.0 - rLre, nim = -rLim;
        const double dre = 1.0 - rre,  dim = -rim;
        const double dm  = dre*dre + dim*dim;
        const double sre = (nre*dre + nim*dim) / dm;
        const double sim = (nim*dre - nre*dim) / dm;
        // W / Lambda
        const double wre = (double)Wri[(h*N_ + n)*2 + 0];
        const double wim = (double)Wri[(h*N_ + n)*2 + 1];
        const double lre = (double)Lre[h*N_ + n], lim = (double)Lim[h*N_ + n];
        const double lm  = lre*lre + lim*lim;
        const double wor = (wre*lre + wim*lim) / lm;
        const double woi = (wim*lre - wre*lim) / lm;
        // c = (W/Lambda) * conj(s) / (|s|^2 + EPS)
        const double sm  = sre*sre + sim*sim + 1e-7;
        const double cre = (wor*sre + woi*sim) / sm;
        const double cim = (woi*sre - wor*sim) / sm;
        // q = r^LC
        const double eC = exp(ad * (double)LC);
        s_rre[n] = (float)rre;  s_rim[n] = (float)rim;
        s_cre[n] = (float)cre;  s_cim[n] = (float)cim;
        s_qre[n] = (float)(eC * cos(bd * (double)LC));
        s_qim[n] = (float)(eC * sin(bd * (double)LC));
    }
    __syncthreads();

    const int k = t >> 3;       // chunk owned by this lane's 8-lane group
    const int g = t & 7;        // lane within group (8 modes each)
    const int base = k * LC;

    float rre[MPL], rim[MPL], ccr[MPL], cci[MPL];
    #pragma unroll
    for (int m = 0; m < MPL; ++m) {
        const int n = g*MPL + m;
        rre[m] = s_rre[n]; rim[m] = s_rim[n];
        ccr[m] = s_cre[n]; cci[m] = s_cim[n];
    }

    float xr[MPL], xi[MPL];
    #pragma unroll
    for (int m = 0; m < MPL; ++m) { xr[m] = 0.f; xi[m] = 0.f; }

    // ---- phase 1: local end-state of each chunk (zero carry-in) ----
    #pragma unroll 2
    for (int j = 0; j < LC; j += 4) {
        const float4 u4 = *reinterpret_cast<const float4*>(&su[base + j]);
        const float uu[4] = {u4.x, u4.y, u4.z, u4.w};
        #pragma unroll
        for (int ss = 0; ss < 4; ++ss) {
            const float uv = uu[ss];
            #pragma unroll
            for (int m = 0; m < MPL; ++m) {
                const float nr = fmaf(rre[m], xr[m], fmaf(-rim[m], xi[m], uv));
                const float ni = fmaf(rre[m], xi[m], rim[m]*xr[m]);
                xr[m] = nr; xi[m] = ni;
            }
        }
    }
    #pragma unroll
    for (int m = 0; m < MPL; m += 2) {
        const float4 v = make_float4(xr[m], xi[m], xr[m+1], xi[m+1]);
        *reinterpret_cast<float4*>(&sE[(k*N_ + g*MPL + m)*2]) = v;
    }
    __syncthreads();

    // ---- phase 2: serial carry scan over chunks (wave 0, one mode per lane) ----
    // in-place: E[k][n] <- carry_k (state just before chunk k), carry_{k+1} = q*carry_k + E_k
    if (t < N_) {
        const int n = t;
        const float qre = s_qre[n], qim = s_qim[n];
        float cr = 0.f, ci = 0.f;
        for (int kk = 0; kk < NCH; ++kk) {
            float2* p = reinterpret_cast<float2*>(&sE[(kk*N_ + n)*2]);
            const float2 e = *p;
            *p = make_float2(cr, ci);
            const float ncr = fmaf(qre, cr, fmaf(-qim, ci, e.x));
            const float nci = fmaf(qre, ci, fmaf(qim, cr, e.y));
            cr = ncr; ci = nci;
        }
    }
    __syncthreads();

    // ---- phase 3: recompute with carry-in, emit y (sE region reused; safe:
    // chunk k's region is read (carries) and written (y) only by its own wave) ----
    #pragma unroll
    for (int m = 0; m < MPL; m += 2) {
        const float4 v = *reinterpret_cast<const float4*>(&sE[(k*N_ + g*MPL + m)*2]);
        xr[m] = v.x; xi[m] = v.y; xr[m+1] = v.z; xi[m+1] = v.w;
    }
    #pragma unroll 2
    for (int j = 0; j < LC; j += 4) {
        const float4 u4 = *reinterpret_cast<const float4*>(&su[base + j]);
        const float uu[4] = {u4.x, u4.y, u4.z, u4.w};
        #pragma unroll
        for (int ss = 0; ss < 4; ++ss) {
            const float uv = uu[ss];
            float acc = 0.f;
            #pragma unroll
            for (int m = 0; m < MPL; ++m) {
                const float nr = fmaf(rre[m], xr[m], fmaf(-rim[m], xi[m], uv));
                const float ni = fmaf(rre[m], xi[m], rim[m]*xr[m]);
                xr[m] = nr; xi[m] = ni;
                acc = fmaf(ccr[m],  nr, acc);
                acc = fmaf(-cci[m], ni, acc);
            }
            acc += __shfl_xor(acc, 1);
            acc += __shfl_xor(acc, 2);
            acc += __shfl_xor(acc, 4);
            if (g == 0) sE[base + j + ss] = acc;
        }
    }
    __syncthreads();

    // ---- flush: y + D*u, coalesced ----
    {
        const float Dh = Dv[h];
        float4* op = reinterpret_cast<float4*>(out + (size_t)bh * L_);
        const float4* yp = reinterpret_cast<const float4*>(sE);
        const float4* sp = reinterpret_cast<const float4*>(su);
        #pragma unroll
        for (int i = 0; i < L_/4/TPB; ++i) {
            float4 y = yp[t + i*TPB];
            const float4 uu = sp[t + i*TPB];
            y.x = fmaf(Dh, uu.x, y.x);
            y.y = fmaf(Dh, uu.y, y.y);
            y.z = fmaf(Dh, uu.z, y.z);
            y.w = fmaf(Dh, uu.w, y.w);
            op[t + i*TPB] = y;
        }
    }
}

extern "C" void kernel_launch(void* const* d_in, const int* in_sizes, int n_in,
                              void* d_out, int out_size, void* d_ws, size_t ws_size,
                              hipStream_t stream) {
    const float* u  = (const float*)d_in[0];
    const float* lr = (const float*)d_in[1];
    const float* li = (const float*)d_in[2];
    const float* w  = (const float*)d_in[3];
    const float* dv = (const float*)d_in[4];
    const float* ls = (const float*)d_in[5];
    float* out = (float*)d_out;
    dss_fwd<<<dim3(B_*H_), dim3(TPB), 0, stream>>>(u, lr, li, w, dv, ls, out);
}